// Round 5
// baseline (261.092 us; speedup 1.0000x reference)
//
#include <hip/hip_runtime.h>
#include <math.h>

#define F_IN 256
#define H1 8
#define C1 128
#define HC1 1024
#define C2 128
#define SLOPE 0.2f

typedef unsigned short u16;
typedef __attribute__((ext_vector_type(8))) short bf16x8;
typedef __attribute__((ext_vector_type(4))) float f32x4;
typedef __attribute__((ext_vector_type(2))) float f32x2;

// ---------------- helpers ----------------

__device__ __forceinline__ float lrelu(float v) { return v > 0.f ? v : SLOPE * v; }

__device__ __forceinline__ unsigned bf16_rne(float x) {
    unsigned u = __float_as_uint(x);
    u += 0x7fffu + ((u >> 16) & 1u);
    return u >> 16;
}

// split a,b into packed-bf16 hi pair and lo pair (lo = exact residual, rounded)
__device__ __forceinline__ void split2(float a, float b, unsigned& hi, unsigned& lo) {
    unsigned ha = bf16_rne(a), hb = bf16_rne(b);
    float fa = __uint_as_float(ha << 16), fb = __uint_as_float(hb << 16);
    hi = ha | (hb << 16);
    lo = bf16_rne(a - fa) | (bf16_rne(b - fb) << 16);
}

__device__ __forceinline__ void gload16(const u16* g, u16* l) {
    __builtin_amdgcn_global_load_lds(
        (const __attribute__((address_space(1))) unsigned*)g,
        (__attribute__((address_space(3))) unsigned*)l, 16, 0, 0);
}

// ---------------- edge sorting (counting sort by dst) ----------------

__global__ void init_deg(int* deg, int n) {
    int i = blockIdx.x * blockDim.x + threadIdx.x;
    if (i < n) deg[i] = 1;  // self-loop
}

__global__ void hist_kernel(const int* __restrict__ dst, int* __restrict__ deg, int E) {
    int i = blockIdx.x * blockDim.x + threadIdx.x;
    if (i < E) atomicAdd(&deg[dst[i]], 1);
}

__global__ void scan_kernel(const int* __restrict__ deg, int* __restrict__ start,
                            int* __restrict__ cursor, int n) {
    __shared__ int buf[1024];
    int carry = 0;
    for (int base = 0; base < n; base += 1024) {
        int i = base + (int)threadIdx.x;
        int v = (i < n) ? deg[i] : 0;
        buf[threadIdx.x] = v;
        __syncthreads();
        for (int offd = 1; offd < 1024; offd <<= 1) {
            int tv = 0;
            if ((int)threadIdx.x >= offd) tv = buf[threadIdx.x - offd];
            __syncthreads();
            if ((int)threadIdx.x >= offd) buf[threadIdx.x] += tv;
            __syncthreads();
        }
        int incl = buf[threadIdx.x];
        if (i < n) { start[i] = carry + incl - v; cursor[i] = carry + incl - v; }
        carry += buf[1023];
        __syncthreads();
    }
    if (threadIdx.x == 0) start[n] = carry;
}

__global__ void scatter_kernel(const int* __restrict__ src, const int* __restrict__ dst,
                               int* __restrict__ cursor, int* __restrict__ ssorted,
                               int E, int N) {
    int i = blockIdx.x * blockDim.x + threadIdx.x;
    if (i < E) {
        int d = dst[i];
        int pos = atomicAdd(&cursor[d], 1);
        ssorted[pos] = src[i];
    } else if (i < E + N) {
        int d = i - E;
        int pos = atomicAdd(&cursor[d], 1);
        ssorted[pos] = d;
    }
}

// ---------------- fp32 -> bf16 hi/lo split ----------------

__global__ void split_mat(const float* __restrict__ in, u16* __restrict__ hi,
                          u16* __restrict__ lo, int n) {
    int i = blockIdx.x * blockDim.x + threadIdx.x;
    if (i >= n) return;
    float v = in[i];
    unsigned h = bf16_rne(v);
    hi[i] = (u16)h;
    lo[i] = (u16)bf16_rne(v - __uint_as_float(h << 16));
}

// in [R][C] -> out [C][R]
__global__ void split_transpose(const float* __restrict__ in, u16* __restrict__ hi,
                                u16* __restrict__ lo, int R, int C) {
    int i = blockIdx.x * blockDim.x + threadIdx.x;
    if (i >= R * C) return;
    int r = i / C, c = i % C;
    float v = in[i];
    unsigned h = bf16_rne(v);
    hi[(size_t)c * R + r] = (u16)h;
    lo[(size_t)c * R + r] = (u16)bf16_rne(v - __uint_as_float(h << 16));
}

// ---------------- split-bf16 MFMA GEMM, 128x128 tile ----------------
// C[M,N](bf16) = (Ahi+Alo)[M,K] @ (Bhi+Blo)^T[N,K], fp32 accumulate.

__global__ __launch_bounds__(256) void gemm_mfma(const u16* __restrict__ Ahi,
                                                 const u16* __restrict__ Alo,
                                                 const u16* __restrict__ Bhi,
                                                 const u16* __restrict__ Blo,
                                                 u16* __restrict__ Cbf,
                                                 int M, int N, int K) {
    __shared__ u16 lds[16384];  // 4 tiles x [128][32] bf16 = 32 KB
    const int t = threadIdx.x;
    const int rbase = blockIdx.y * 128;
    const int cbase = blockIdx.x * 128;

    const int lane = t & 63;
    const int R0 = (t >> 7) << 6;
    const int C0 = ((t >> 6) & 1) << 6;
    const int lrow = lane & 15;
    const int kq = lane >> 4;

    f32x4 acc[4][4] = {};

    for (int k0 = 0; k0 < K; k0 += 32) {
#pragma unroll
        for (int i = 0; i < 2; i++) {
            int c = t + (i << 8);
            int row = c >> 2;
            int kc = (c & 3) << 3;
            int ar = min(rbase + row, M - 1);
            int br = cbase + row;
            gload16(Ahi + (size_t)ar * K + k0 + kc, &lds[c * 8]);
            gload16(Alo + (size_t)ar * K + k0 + kc, &lds[4096 + c * 8]);
            gload16(Bhi + (size_t)br * K + k0 + kc, &lds[8192 + c * 8]);
            gload16(Blo + (size_t)br * K + k0 + kc, &lds[12288 + c * 8]);
        }
        __syncthreads();

        bf16x8 ah[4], al[4], bh[4], bl[4];
#pragma unroll
        for (int m = 0; m < 4; m++) {
            int off = (R0 + (m << 4) + lrow) * 32 + (kq << 3);
            ah[m] = *(const bf16x8*)&lds[off];
            al[m] = *(const bf16x8*)&lds[4096 + off];
        }
#pragma unroll
        for (int n = 0; n < 4; n++) {
            int off = (C0 + (n << 4) + lrow) * 32 + (kq << 3);
            bh[n] = *(const bf16x8*)&lds[8192 + off];
            bl[n] = *(const bf16x8*)&lds[12288 + off];
        }
#pragma unroll
        for (int m = 0; m < 4; m++)
#pragma unroll
            for (int n = 0; n < 4; n++) {
                acc[m][n] = __builtin_amdgcn_mfma_f32_16x16x32_bf16(ah[m], bh[n], acc[m][n], 0, 0, 0);
                acc[m][n] = __builtin_amdgcn_mfma_f32_16x16x32_bf16(ah[m], bl[n], acc[m][n], 0, 0, 0);
                acc[m][n] = __builtin_amdgcn_mfma_f32_16x16x32_bf16(al[m], bh[n], acc[m][n], 0, 0, 0);
            }
        __syncthreads();
    }

#pragma unroll
    for (int m = 0; m < 4; m++)
#pragma unroll
        for (int n = 0; n < 4; n++) {
            int col = cbase + C0 + (n << 4) + lrow;
#pragma unroll
            for (int r = 0; r < 4; r++) {
                int row = rbase + R0 + (m << 4) + kq * 4 + r;
                if (row < M) Cbf[(size_t)row * N + col] = (u16)bf16_rne(acc[m][n][r]);
            }
        }
}

// ---------------- split-bf16 MFMA GEMM, 64x64 tile (more blocks; for GEMM2) ----

__global__ __launch_bounds__(256) void gemm_mfma64(const u16* __restrict__ Ahi,
                                                   const u16* __restrict__ Alo,
                                                   const u16* __restrict__ Bhi,
                                                   const u16* __restrict__ Blo,
                                                   u16* __restrict__ Cbf,
                                                   int M, int N, int K) {
    __shared__ u16 lds[8192];  // 4 tiles x [64][32] bf16 = 16 KB
    const int t = threadIdx.x;
    const int rbase = blockIdx.y * 64;
    const int cbase = blockIdx.x * 64;

    const int lane = t & 63;
    const int w = t >> 6;
    const int R0 = (w >> 1) << 5;   // 0 / 32
    const int C0 = (w & 1) << 5;    // 0 / 32
    const int lrow = lane & 15;
    const int kq = lane >> 4;

    f32x4 acc[2][2] = {};

    for (int k0 = 0; k0 < K; k0 += 32) {
        {
            int row = t >> 2;
            int kc = (t & 3) << 3;
            int ar = min(rbase + row, M - 1);
            int br = cbase + row;
            gload16(Ahi + (size_t)ar * K + k0 + kc, &lds[t * 8]);
            gload16(Alo + (size_t)ar * K + k0 + kc, &lds[2048 + t * 8]);
            gload16(Bhi + (size_t)br * K + k0 + kc, &lds[4096 + t * 8]);
            gload16(Blo + (size_t)br * K + k0 + kc, &lds[6144 + t * 8]);
        }
        __syncthreads();

        bf16x8 ah[2], al[2], bh[2], bl[2];
#pragma unroll
        for (int m = 0; m < 2; m++) {
            int off = (R0 + (m << 4) + lrow) * 32 + (kq << 3);
            ah[m] = *(const bf16x8*)&lds[off];
            al[m] = *(const bf16x8*)&lds[2048 + off];
        }
#pragma unroll
        for (int n = 0; n < 2; n++) {
            int off = (C0 + (n << 4) + lrow) * 32 + (kq << 3);
            bh[n] = *(const bf16x8*)&lds[4096 + off];
            bl[n] = *(const bf16x8*)&lds[6144 + off];
        }
#pragma unroll
        for (int m = 0; m < 2; m++)
#pragma unroll
            for (int n = 0; n < 2; n++) {
                acc[m][n] = __builtin_amdgcn_mfma_f32_16x16x32_bf16(ah[m], bh[n], acc[m][n], 0, 0, 0);
                acc[m][n] = __builtin_amdgcn_mfma_f32_16x16x32_bf16(ah[m], bl[n], acc[m][n], 0, 0, 0);
                acc[m][n] = __builtin_amdgcn_mfma_f32_16x16x32_bf16(al[m], bh[n], acc[m][n], 0, 0, 0);
            }
        __syncthreads();
    }

#pragma unroll
    for (int m = 0; m < 2; m++)
#pragma unroll
        for (int n = 0; n < 2; n++) {
            int col = cbase + C0 + (n << 4) + lrow;
#pragma unroll
            for (int r = 0; r < 4; r++) {
                int row = rbase + R0 + (m << 4) + kq * 4 + r;
                if (row < M) Cbf[(size_t)row * N + col] = (u16)bf16_rne(acc[m][n][r]);
            }
        }
}

// ---------------- attention scores (bf16 h input) ----------------

__global__ __launch_bounds__(256) void scores1_bf(const unsigned* __restrict__ hbf,
                                                  const float* __restrict__ a_s,
                                                  const float* __restrict__ a_d,
                                                  float* __restrict__ ssrc,
                                                  float* __restrict__ sdst, int N) {
    int wid = blockIdx.x * 4 + (threadIdx.x >> 6);
    if (wid >= N * H1) return;
    int lane = threadIdx.x & 63;
    int n = wid >> 3, hh = wid & 7;
    unsigned u = hbf[(size_t)n * 512 + hh * 64 + lane];
    float c0 = __uint_as_float(u << 16);
    float c1 = __uint_as_float(u & 0xffff0000u);
    const float* as = a_s + hh * C1;
    const float* ad = a_d + hh * C1;
    float vs = c0 * as[2 * lane] + c1 * as[2 * lane + 1];
    float vd = c0 * ad[2 * lane] + c1 * ad[2 * lane + 1];
    for (int off = 32; off; off >>= 1) {
        vs += __shfl_xor(vs, off);
        vd += __shfl_xor(vd, off);
    }
    if (lane == 0) { ssrc[wid] = vs; sdst[wid] = vd; }
}

__global__ __launch_bounds__(256) void scores2_bf(const unsigned* __restrict__ hbf,
                                                  const float* __restrict__ a_s,
                                                  const float* __restrict__ a_d,
                                                  float* __restrict__ ssrc,
                                                  float* __restrict__ sdst, int N) {
    int n = blockIdx.x * 4 + (threadIdx.x >> 6);
    if (n >= N) return;
    int lane = threadIdx.x & 63;
    unsigned u = hbf[(size_t)n * 64 + lane];
    float c0 = __uint_as_float(u << 16);
    float c1 = __uint_as_float(u & 0xffff0000u);
    float vs = c0 * a_s[2 * lane] + c1 * a_s[2 * lane + 1];
    float vd = c0 * a_d[2 * lane] + c1 * a_d[2 * lane + 1];
    for (int off = 32; off; off >>= 1) {
        vs += __shfl_xor(vs, off);
        vd += __shfl_xor(vd, off);
    }
    if (lane == 0) { ssrc[n] = vs; sdst[n] = vd; }
}

// ---------------- aggregation: one wave per (dst, head) ----------------
// Pass 3 uses a wave-private LDS (byte_offset, alpha) pair buffer instead of
// shuffle broadcasts: the gather loop is ds_read_b64 -> add -> dwordx4 load ->
// 8 FMA, with no bpermute chain, so loads pipeline across unrolled iterations.
// 4 edges per iteration: 16-lane group g handles edge e2+g, lane loads uint4
// (8 channels). Cross-group shuffle reduction at the end.
// H=8: head = blockIdx.x % 8 -> one head per XCD (L2-resident 2.56 MB slice).

template<int H, bool SPLITOUT>
__global__ __launch_bounds__(256) void agg_bf(const unsigned* __restrict__ hbf,
                                              const float* __restrict__ ssrc,
                                              const float* __restrict__ sdst,
                                              const int* __restrict__ start,
                                              const int* __restrict__ ssorted,
                                              const float* __restrict__ bias,
                                              float* __restrict__ out,
                                              unsigned* __restrict__ outHi,
                                              unsigned* __restrict__ outLo, int N) {
    constexpr int CH = 128;               // pairs per chunk
    __shared__ int2 pairs[4][CH + 4];     // wave-private slices, no barriers
    int hh, grp;
    if (H == 8) { hh = blockIdx.x & 7; grp = blockIdx.x >> 3; }
    else        { hh = 0;              grp = blockIdx.x; }
    int wid = threadIdx.x >> 6, lane = threadIdx.x & 63;
    int d = grp * 4 + wid;
    if (d >= N) return;
    const int g = lane >> 4, p = lane & 15;
    int s0 = start[d];
    int ne = start[d + 1] - s0;
    float sd = sdst[d * H + hh];
    const int rowbytes = H * 256;                       // bytes per node-row
    const char* hbase = (const char*)hbf + hh * 256 + p * 16;

    // pass 1: max (strided, register-only)
    float m = -1e30f;
    for (int e = lane; e < ne; e += 64)
        m = fmaxf(m, lrelu(ssrc[ssorted[s0 + e] * H + hh] + sd));
    for (int o = 32; o; o >>= 1) m = fmaxf(m, __shfl_xor(m, o));

    // pass 2: denom
    float ssum = 0.f;
    for (int e = lane; e < ne; e += 64)
        ssum += __expf(lrelu(ssrc[ssorted[s0 + e] * H + hh] + sd) - m);
    for (int o = 32; o; o >>= 1) ssum += __shfl_xor(ssum, o);
    float inv = 1.f / ssum;

    // pass 3: chunked fill + gather
    f32x2 acc0 = {0.f, 0.f}, acc1 = {0.f, 0.f}, acc2 = {0.f, 0.f}, acc3 = {0.f, 0.f};
    for (int c0 = 0; c0 < ne; c0 += CH) {
        int cn = min(CH, ne - c0);
        int cn4 = (cn + 3) & ~3;
        for (int e = lane; e < cn4; e += 64) {
            int2 pr = make_int2(0, 0);   // padded: alpha=0, row 0 (valid mem)
            if (e < cn) {
                int sr = ssorted[s0 + c0 + e];
                float a = __expf(lrelu(ssrc[sr * H + hh] + sd) - m) * inv;
                pr = make_int2(sr * rowbytes, __float_as_int(a));
            }
            pairs[wid][e] = pr;
        }
#pragma unroll 2
        for (int e2 = 0; e2 < cn4; e2 += 4) {
            int2 pr = pairs[wid][e2 + g];
            float a = __int_as_float(pr.y);
            uint4 u = *(const uint4*)(hbase + pr.x);
            f32x2 av = {a, a};
            f32x2 f0 = {__uint_as_float(u.x << 16), __uint_as_float(u.x & 0xffff0000u)};
            f32x2 f1 = {__uint_as_float(u.y << 16), __uint_as_float(u.y & 0xffff0000u)};
            f32x2 f2 = {__uint_as_float(u.z << 16), __uint_as_float(u.z & 0xffff0000u)};
            f32x2 f3 = {__uint_as_float(u.w << 16), __uint_as_float(u.w & 0xffff0000u)};
            acc0 += av * f0;
            acc1 += av * f1;
            acc2 += av * f2;
            acc3 += av * f3;
        }
    }

    float acc[8] = {acc0.x, acc0.y, acc1.x, acc1.y, acc2.x, acc2.y, acc3.x, acc3.y};
    // cross-group reduction: lanes with same p hold the same 8 channels
#pragma unroll
    for (int i = 0; i < 8; i++) {
        acc[i] += __shfl_xor(acc[i], 16);
        acc[i] += __shfl_xor(acc[i], 32);
    }

    // group g writes u32-pair index 4p+g = channels (8p+2g, 8p+2g+1)
    float r0 = g == 0 ? acc[0] : g == 1 ? acc[2] : g == 2 ? acc[4] : acc[6];
    float r1 = g == 0 ? acc[1] : g == 1 ? acc[3] : g == 2 ? acc[5] : acc[7];
    int j = 4 * p + g;
    float2 bv = ((const float2*)bias)[hh * 64 + j];
    r0 += bv.x; r1 += bv.y;
    size_t idx = (size_t)d * (H * 64) + hh * 64 + j;
    if (SPLITOUT) {
        r0 = r0 > 0.f ? r0 : expm1f(r0);
        r1 = r1 > 0.f ? r1 : expm1f(r1);
        unsigned hi, lo;
        split2(r0, r1, hi, lo);
        outHi[idx] = hi;
        outLo[idx] = lo;
    } else {
        ((float2*)out)[idx] = make_float2(r0, r1);
    }
}

// ---------------- launch ----------------

extern "C" void kernel_launch(void* const* d_in, const int* in_sizes, int n_in,
                              void* d_out, int out_size, void* d_ws, size_t ws_size,
                              hipStream_t stream) {
    const float* x      = (const float*)d_in[0];
    const int*   ei     = (const int*)d_in[1];
    const float* W1     = (const float*)d_in[2];
    const float* a_src1 = (const float*)d_in[3];
    const float* a_dst1 = (const float*)d_in[4];
    const float* b1     = (const float*)d_in[5];
    const float* W2     = (const float*)d_in[6];
    const float* a_src2 = (const float*)d_in[7];
    const float* a_dst2 = (const float*)d_in[8];
    const float* b2     = (const float*)d_in[9];
    float* out = (float*)d_out;

    int E = in_sizes[1] / 2;
    int N = in_sizes[0] / F_IN;
    const int* esrc = ei;
    const int* edst = ei + E;

    char* ws = (char*)d_ws;
    size_t off = 0;
    auto alloc = [&](size_t bytes) -> char* {
        char* p = ws + off;
        off = (off + bytes + 255) & ~(size_t)255;
        return p;
    };
    u16* x_hi    = (u16*)alloc((size_t)N * F_IN * 2);
    u16* x_lo    = (u16*)alloc((size_t)N * F_IN * 2);
    u16* W1t_hi  = (u16*)alloc((size_t)F_IN * HC1 * 2);
    u16* W1t_lo  = (u16*)alloc((size_t)F_IN * HC1 * 2);
    u16* W2t_hi  = (u16*)alloc((size_t)HC1 * C2 * 2);
    u16* W2t_lo  = (u16*)alloc((size_t)HC1 * C2 * 2);
    u16* h1_bf   = (u16*)alloc((size_t)N * HC1 * 2);
    u16* h1a_hi  = (u16*)alloc((size_t)N * HC1 * 2);
    u16* h1a_lo  = (u16*)alloc((size_t)N * HC1 * 2);
    u16* h2_bf   = (u16*)alloc((size_t)N * C2 * 2);
    float* ss1   = (float*)alloc((size_t)N * H1 * 4);
    float* sd1   = (float*)alloc((size_t)N * H1 * 4);
    float* ss2   = (float*)alloc((size_t)N * 4);
    float* sd2   = (float*)alloc((size_t)N * 4);
    int* deg     = (int*)alloc((size_t)N * 4);
    int* startp  = (int*)alloc((size_t)(N + 1) * 4);
    int* cursor  = (int*)alloc((size_t)N * 4);
    int* ssorted = (int*)alloc((size_t)(E + N) * 4);

    // edge sort by destination
    init_deg<<<(N + 255) / 256, 256, 0, stream>>>(deg, N);
    hist_kernel<<<(E + 255) / 256, 256, 0, stream>>>(edst, deg, E);
    scan_kernel<<<1, 1024, 0, stream>>>(deg, startp, cursor, N);
    scatter_kernel<<<(E + N + 255) / 256, 256, 0, stream>>>(esrc, edst, cursor, ssorted, E, N);

    // operand splits
    split_mat<<<(N * F_IN + 255) / 256, 256, 0, stream>>>(x, x_hi, x_lo, N * F_IN);
    split_transpose<<<(F_IN * HC1 + 255) / 256, 256, 0, stream>>>(W1, W1t_hi, W1t_lo, F_IN, HC1);
    split_transpose<<<(HC1 * C2 + 255) / 256, 256, 0, stream>>>(W2, W2t_hi, W2t_lo, HC1, C2);

    // layer 1
    gemm_mfma<<<dim3(HC1 / 128, (N + 127) / 128), 256, 0, stream>>>(
        x_hi, x_lo, W1t_hi, W1t_lo, h1_bf, N, HC1, F_IN);
    scores1_bf<<<(N * H1 + 3) / 4, 256, 0, stream>>>(
        (const unsigned*)h1_bf, a_src1, a_dst1, ss1, sd1, N);
    agg_bf<H1, true><<<((N + 3) / 4) * H1, 256, 0, stream>>>(
        (const unsigned*)h1_bf, ss1, sd1, startp, ssorted, b1,
        nullptr, (unsigned*)h1a_hi, (unsigned*)h1a_lo, N);

    // layer 2 (64x64 tiles -> 314 blocks vs 79)
    gemm_mfma64<<<dim3(C2 / 64, (N + 63) / 64), 256, 0, stream>>>(
        h1a_hi, h1a_lo, W2t_hi, W2t_lo, h2_bf, N, C2, HC1);
    scores2_bf<<<(N + 3) / 4, 256, 0, stream>>>(
        (const unsigned*)h2_bf, a_src2, a_dst2, ss2, sd2, N);
    agg_bf<1, false><<<(N + 3) / 4, 256, 0, stream>>>(
        (const unsigned*)h2_bf, ss2, sd2, startp, ssorted, b2,
        out, nullptr, nullptr, N);
}